// Round 12
// baseline (374.022 us; speedup 1.0000x reference)
//
#include <hip/hip_runtime.h>

// RNN: h_t = tanh(x_t * W_ih^T + b_ih + h_{t-1} W_hh^T + b_hh), out = h_T W_fc^T + b_fc
// B=8192, T=784, I=1, H=30 (pad 32), C=10. fp32.
//
// R14 = R12 (proven 222us: two-wave tile split, parity double-buffer, one
// barrier/step, zero-shuffle permuted-A, bf16 split-float, exp2 tanh) +
// TWO-TILE IN-WAVE INTERLEAVE. R12 is chain-bound: 686 clk/step = 283
// issue + ~400 exposed (pack->write-drain->barrier->ds_read(120)->MFMA->
// tanh), with 1 wave/SIMD there is no co-resident work to fill the stall,
// and R10/R13 showed scheduler consolidation / same-wave extra issue both
// lose. Fix: each wave-pair carries TWO independent 16-batch tiles (A,B).
// One barrier serves both; the four post-barrier b128 reads issue
// back-to-back (latencies overlap); tile B's MFMA+tanh issue fills tile
// A's read/MFMA/tanh latency and vice versa. Chain paid once per period,
// issue doubled: P ~ max(2x283, chain) ~ 560-600 for TWO tile-steps.
// Also: 3 INDEPENDENT MFMA chains per tile (R13's one good lesson;
// 2 extra vector adds, -35 clk chain depth, no masking overhead).
// Numerics byte-identical to R12 (absmax 0.001953125 expected).

#define BB 8192
#define TT 784
#define HH 30
#define CC 10

typedef __attribute__((ext_vector_type(8))) short  bf16x8;
typedef __attribute__((ext_vector_type(4))) float  f32x4;
typedef __attribute__((ext_vector_type(4))) unsigned uint4v;

#if __has_builtin(__builtin_amdgcn_exp2f)
#define EXP2(v) __builtin_amdgcn_exp2f(v)
#else
#define EXP2(v) __expf((v) * 0.69314718055994531f)   // e^(x ln2) = 2^x
#endif

// pre-scale folded into W_hh/W_ih/bias: 2*log2(e)
#define SCL 2.8853900817779268f

__device__ __forceinline__ float tanh_e2(float s) {
    // s = 2*log2e*a ;  tanh(a) = 1 - 2/(2^s + 1)
    return 1.0f - 2.0f * __builtin_amdgcn_rcpf(EXP2(s) + 1.0f);
}

// (p0,p1) f32 -> packed bf16 pair hp (hi) + packed bf16 residual pair lp.
#define BPAIR(p0, p1, hp, lp) do {                                          \
    asm("v_cvt_pk_bf16_f32 %0, %1, %2" : "=v"(hp) : "v"(p0), "v"(p1));      \
    const float _h0 = __uint_as_float((hp) << 16);                          \
    const float _h1 = __uint_as_float((hp) & 0xffff0000u);                  \
    const float _l0 = (p0) - _h0;                                           \
    const float _l1 = (p1) - _h1;                                           \
    asm("v_cvt_pk_bf16_f32 %0, %1, %2" : "=v"(lp) : "v"(_l0), "v"(_l1));    \
} while (0)

#define MFMA(A, B, C) __builtin_amdgcn_mfma_f32_16x16x32_bf16((A), (B), (C), 0, 0, 0)

__global__ __launch_bounds__(128)
__attribute__((amdgpu_waves_per_eu(1, 1)))
void rnn_scan_kernel(const float* __restrict__ x,
                     const float* __restrict__ W_ih,
                     const float* __restrict__ W_hh,
                     const float* __restrict__ b_ih,
                     const float* __restrict__ b_hh,
                     const float* __restrict__ W_fc,
                     const float* __restrict__ b_fc,
                     float* __restrict__ out) {
    // [parity][tile][lane][wv]; b128 read of [lane][0..1] = full packed frag.
    __shared__ unsigned long long Ehi[2][2][64][2];
    __shared__ unsigned long long Elo[2][2][64][2];
    __shared__ float hfc[32][33];

    const int tid  = threadIdx.x;
    const int wv   = tid >> 6;        // 0: h rows j=0..3, 1: rows j=4..7
    const int lane = tid & 63;
    const int n    = lane & 15;       // batch column / A-tile row
    const int g    = lane >> 4;       // k-group / D-row group
    const int bA   = blockIdx.x * 32 + n;        // tile A batch
    const int bB   = bA + 16;                    // tile B batch

    // ---- A fragment (R12-proven permutation; shared by both tiles) ----
    const int rr = 8 * (n >> 2) + (n & 3) + 4 * wv;   // 30,31 -> zero rows
    unsigned ah[4], al[4];
#pragma unroll
    for (int d = 0; d < 4; ++d) {
        const int k0 = 8 * g + 2 * d, k1 = k0 + 1;
        const float wa = (rr < HH && k0 < HH) ? SCL * W_hh[rr * HH + k0] : 0.f;
        const float wb = (rr < HH && k1 < HH) ? SCL * W_hh[rr * HH + k1] : 0.f;
        const unsigned ua = __float_as_uint(wa), ub = __float_as_uint(wb);
        ah[d] = (ub & 0xffff0000u) | (ua >> 16);
        const float la = wa - __uint_as_float(ua & 0xffff0000u);
        const float lb = wb - __uint_as_float(ub & 0xffff0000u);
        al[d] = (__float_as_uint(lb) & 0xffff0000u) | (__float_as_uint(la) >> 16);
    }
    bf16x8 Ah = __builtin_bit_cast(bf16x8, (uint4v){ah[0], ah[1], ah[2], ah[3]});
    bf16x8 Al = __builtin_bit_cast(bf16x8, (uint4v){al[0], al[1], al[2], al[3]});
    asm volatile("" : "+v"(Ah), "+v"(Al));

    // ---- C-init params (shared): D rows are h rows 8g+4wv+r ----
    float bias[4], wih[4];
#pragma unroll
    for (int r = 0; r < 4; ++r) {
        const int q = 8 * g + 4 * wv + r;             // 30,31 -> zero
        bias[r] = (q < HH) ? SCL * (b_ih[q] + b_hh[q]) : 0.f;
        wih[r]  = (q < HH) ? SCL * W_ih[q] : 0.f;
        asm volatile("" : "+v"(bias[r]), "+v"(wih[r]));
    }

    // own h state per tile; rows 30/31: acc==0 -> tanh_e2(0)=0 exactly.
    float hA0 = 0.f, hA1 = 0.f, hA2 = 0.f, hA3 = 0.f;
    float hB0 = 0.f, hB1 = 0.f, hB2 = 0.f, hB3 = 0.f;

    const float* xpA = x + (size_t)bA * TT;
    const float* xpB = x + (size_t)bB * TT;
    const int NQ = TT / 4;
    float4 xqA = *(const float4*)xpA;
    float4 xnA = *(const float4*)(xpA + 4);
    float4 xqB = *(const float4*)xpB;
    float4 xnB = *(const float4*)(xpB + 4);

    for (int qq = 0; qq < NQ; ++qq) {
        const bool more = (qq + 2 < NQ);
        const float4 xfA = more ? *(const float4*)(xpA + (qq + 2) * 4)
                                : make_float4(0.f, 0.f, 0.f, 0.f);
        const float4 xfB = more ? *(const float4*)(xpB + (qq + 2) * 4)
                                : make_float4(0.f, 0.f, 0.f, 0.f);
#pragma unroll
        for (int u = 0; u < 4; ++u) {
            const float xtA = (u == 0) ? xqA.x : (u == 1) ? xqA.y
                            : (u == 2) ? xqA.z : xqA.w;
            const float xtB = (u == 0) ? xqB.x : (u == 1) ? xqB.y
                            : (u == 2) ? xqB.z : xqB.w;
            const int p = u & 1;   // step parity

            // 1. pack + publish both tiles' own halves
            unsigned hp0, hp1, lp0, lp1;
            BPAIR(hA0, hA1, hp0, lp0);
            BPAIR(hA2, hA3, hp1, lp1);
            Ehi[p][0][lane][wv] = (unsigned long long)hp0 |
                                  ((unsigned long long)hp1 << 32);
            Elo[p][0][lane][wv] = (unsigned long long)lp0 |
                                  ((unsigned long long)lp1 << 32);
            unsigned hq0, hq1, lq0, lq1;
            BPAIR(hB0, hB1, hq0, lq0);
            BPAIR(hB2, hB3, hq1, lq1);
            Ehi[p][1][lane][wv] = (unsigned long long)hq0 |
                                  ((unsigned long long)hq1 << 32);
            Elo[p][1][lane][wv] = (unsigned long long)lq0 |
                                  ((unsigned long long)lq1 << 32);

            // 2. C-inits (overlap barrier wait)
            f32x4 accA = { fmaf(xtA, wih[0], bias[0]), fmaf(xtA, wih[1], bias[1]),
                           fmaf(xtA, wih[2], bias[2]), fmaf(xtA, wih[3], bias[3]) };
            f32x4 accB = { fmaf(xtB, wih[0], bias[0]), fmaf(xtB, wih[1], bias[1]),
                           fmaf(xtB, wih[2], bias[2]), fmaf(xtB, wih[3], bias[3]) };

            // 3. exchange (one barrier for both tiles; 4 reads back-to-back)
            __syncthreads();
            const uint4v bhA = *(const uint4v*)&Ehi[p][0][lane][0];
            const uint4v blA = *(const uint4v*)&Elo[p][0][lane][0];
            const uint4v bhB = *(const uint4v*)&Ehi[p][1][lane][0];
            const uint4v blB = *(const uint4v*)&Elo[p][1][lane][0];
            const bf16x8 BhA = __builtin_bit_cast(bf16x8, bhA);
            const bf16x8 BlA = __builtin_bit_cast(bf16x8, blA);
            const bf16x8 BhB = __builtin_bit_cast(bf16x8, bhB);
            const bf16x8 BlB = __builtin_bit_cast(bf16x8, blB);

            // 4. MFMAs: 3 independent chains per tile (depth 1L + adds)
            const f32x4 zed = {0.f, 0.f, 0.f, 0.f};
            accA = MFMA(Ah, BhA, accA);
            f32x4 q1A = MFMA(Ah, BlA, zed);
            f32x4 q2A = MFMA(Al, BhA, zed);
            accB = MFMA(Ah, BhB, accB);
            f32x4 q1B = MFMA(Ah, BlB, zed);
            f32x4 q2B = MFMA(Al, BhB, zed);
            const f32x4 sA = (accA + q1A) + q2A;
            const f32x4 sB = (accB + q1B) + q2B;

            // 5. tanh (input pre-scaled by SCL)
            hA0 = tanh_e2(sA[0]); hA1 = tanh_e2(sA[1]);
            hA2 = tanh_e2(sA[2]); hA3 = tanh_e2(sA[3]);
            hB0 = tanh_e2(sB[0]); hB1 = tanh_e2(sB[1]);
            hB2 = tanh_e2(sB[2]); hB3 = tanh_e2(sB[3]);
        }
        xqA = xnA; xnA = xfA;
        xqB = xnB; xnB = xfB;
    }

    // ---- FC head: gather both tiles' h, each wave outputs its tile ----
    hfc[n     ][8 * g + 4 * wv + 0] = hA0;
    hfc[n     ][8 * g + 4 * wv + 1] = hA1;
    hfc[n     ][8 * g + 4 * wv + 2] = hA2;
    hfc[n     ][8 * g + 4 * wv + 3] = hA3;
    hfc[16 + n][8 * g + 4 * wv + 0] = hB0;
    hfc[16 + n][8 * g + 4 * wv + 1] = hB1;
    hfc[16 + n][8 * g + 4 * wv + 2] = hB2;
    hfc[16 + n][8 * g + 4 * wv + 3] = hB3;
    __syncthreads();
    {
        const int brow = wv * 16 + n;                 // local batch 0..31
        const int bout = blockIdx.x * 32 + brow;
#pragma unroll
        for (int j = 0; j < 3; ++j) {
            const int c = g + 4 * j;                  // covers c=0..9 once
            if (c < CC) {
                float acc = b_fc[c];
#pragma unroll
                for (int k = 0; k < HH; ++k)
                    acc = fmaf(W_fc[c * HH + k], hfc[brow][k], acc);
                out[(size_t)bout * CC + c] = acc;
            }
        }
    }
}

extern "C" void kernel_launch(void* const* d_in, const int* in_sizes, int n_in,
                              void* d_out, int out_size, void* d_ws, size_t ws_size,
                              hipStream_t stream) {
    const float* x    = (const float*)d_in[0];
    const float* W_ih = (const float*)d_in[1];
    const float* W_hh = (const float*)d_in[2];
    const float* b_ih = (const float*)d_in[3];
    const float* b_hh = (const float*)d_in[4];
    const float* W_fc = (const float*)d_in[5];
    const float* b_fc = (const float*)d_in[6];

    hipLaunchKernelGGL(rnn_scan_kernel,
                       dim3(BB / 32), dim3(128), 0, stream,
                       x, W_ih, W_hh, b_ih, b_hh, W_fc, b_fc,
                       (float*)d_out);
}

// Round 13
// 321.370 us; speedup vs baseline: 1.1638x; 1.1638x over previous
//
#include <hip/hip_runtime.h>

// RNN: h_t = tanh(x_t * W_ih^T + b_ih + h_{t-1} W_hh^T + b_hh), out = h_T W_fc^T + b_fc
// B=8192, T=784, I=1, H=30 (pad 32), C=10. fp32.
//
// R15: protocol-hiding via real TLP. Session accounting: R12 (best, 222us)
// = 233 issue + ~453 clk/step EXCHANGE PROTOCOL (write-drain + barrier +
// ds_read latency); R14 proved same-phase in-wave interleave cannot hide
// the protocol (stall unchanged at 476 while issue doubled). Only an
// independent co-resident wave can fill it -> need 2 waves/SIMD, but the
// 16-batch pair decomposition caps at 1024 waves (1/SIMD). Fix: 8 batches
// per 2-wave pair -> 1024 pairs = 2048 waves = 2/SIMD on ALL 256 CUs
// (R10's mistake -- idling half the SIMDs -- avoided). Per-wave issue is
// unchanged (tail is per-lane; B columns 8..15 carry dummy data, isolated
// per-column by MFMA semantics), so per-SIMD period -> max(2x233, ~453)
// ~ 500 clk serving the same 16 batches/SIMD as R12's 686.
// Exchange layout per R13/R14 lesson: ONE b128 write + ONE b128 read per
// wave (B-frags composed from own regs + partner's quad) -> bank conflicts
// 6.4M -> ~8K. Numerics identical to R12/R14 (absmax 0.001953125).

#define BB 8192
#define TT 784
#define HH 30
#define CC 10

typedef __attribute__((ext_vector_type(8))) short  bf16x8;
typedef __attribute__((ext_vector_type(4))) float  f32x4;
typedef __attribute__((ext_vector_type(4))) unsigned uint4v;

#if __has_builtin(__builtin_amdgcn_exp2f)
#define EXP2(v) __builtin_amdgcn_exp2f(v)
#else
#define EXP2(v) __expf((v) * 0.69314718055994531f)   // e^(x ln2) = 2^x
#endif

// pre-scale folded into W_hh/W_ih/bias: 2*log2(e)
#define SCL 2.8853900817779268f

__device__ __forceinline__ float tanh_e2(float s) {
    // s = 2*log2e*a ;  tanh(a) = 1 - 2/(2^s + 1)
    return 1.0f - 2.0f * __builtin_amdgcn_rcpf(EXP2(s) + 1.0f);
}

// (p0,p1) f32 -> packed bf16 pair hp (hi) + packed bf16 residual pair lp.
#define BPAIR(p0, p1, hp, lp) do {                                          \
    asm("v_cvt_pk_bf16_f32 %0, %1, %2" : "=v"(hp) : "v"(p0), "v"(p1));      \
    const float _h0 = __uint_as_float((hp) << 16);                          \
    const float _h1 = __uint_as_float((hp) & 0xffff0000u);                  \
    const float _l0 = (p0) - _h0;                                           \
    const float _l1 = (p1) - _h1;                                           \
    asm("v_cvt_pk_bf16_f32 %0, %1, %2" : "=v"(lp) : "v"(_l0), "v"(_l1));    \
} while (0)

#define MFMA(A, B, C) __builtin_amdgcn_mfma_f32_16x16x32_bf16((A), (B), (C), 0, 0, 0)

__global__ __launch_bounds__(128)
__attribute__((amdgpu_waves_per_eu(2, 2)))
void rnn_scan_kernel(const float* __restrict__ x,
                     const float* __restrict__ W_ih,
                     const float* __restrict__ W_hh,
                     const float* __restrict__ b_ih,
                     const float* __restrict__ b_hh,
                     const float* __restrict__ W_fc,
                     const float* __restrict__ b_fc,
                     float* __restrict__ out) {
    // E[parity][wv][lane] = writer wave's packed own-half {hp0,hp1,lp0,lp1}.
    // Single b128 write / single b128 read: conflict-light (R13 measured 8K).
    __shared__ uint4v E[2][2][64];
    __shared__ float hfc[8][33];

    const int tid  = threadIdx.x;
    const int wv   = tid >> 6;        // 0: h rows j=0..3, 1: rows j=4..7
    const int lane = tid & 63;
    const int n    = lane & 15;       // A-tile row / B column
    const int g    = lane >> 4;       // k-group / D-row group
    const bool live = (n < 8);        // only columns 0..7 are real batches
    const int b    = blockIdx.x * 8 + (live ? n : 0);   // dummies read batch 0

    // ---- A fragment (R12-proven permutation) ----
    const int rr = 8 * (n >> 2) + (n & 3) + 4 * wv;   // 30,31 -> zero rows
    unsigned ah[4], al[4];
#pragma unroll
    for (int d = 0; d < 4; ++d) {
        const int k0 = 8 * g + 2 * d, k1 = k0 + 1;
        const float wa = (rr < HH && k0 < HH) ? SCL * W_hh[rr * HH + k0] : 0.f;
        const float wb = (rr < HH && k1 < HH) ? SCL * W_hh[rr * HH + k1] : 0.f;
        const unsigned ua = __float_as_uint(wa), ub = __float_as_uint(wb);
        ah[d] = (ub & 0xffff0000u) | (ua >> 16);
        const float la = wa - __uint_as_float(ua & 0xffff0000u);
        const float lb = wb - __uint_as_float(ub & 0xffff0000u);
        al[d] = (__float_as_uint(lb) & 0xffff0000u) | (__float_as_uint(la) >> 16);
    }
    bf16x8 Ah = __builtin_bit_cast(bf16x8, (uint4v){ah[0], ah[1], ah[2], ah[3]});
    bf16x8 Al = __builtin_bit_cast(bf16x8, (uint4v){al[0], al[1], al[2], al[3]});
    asm volatile("" : "+v"(Ah), "+v"(Al));

    // ---- C-init params: this lane+wave's D rows are h rows 8g+4wv+r ----
    float bias[4], wih[4];
#pragma unroll
    for (int r = 0; r < 4; ++r) {
        const int q = 8 * g + 4 * wv + r;             // 30,31 -> zero
        bias[r] = (q < HH) ? SCL * (b_ih[q] + b_hh[q]) : 0.f;
        wih[r]  = (q < HH) ? SCL * W_ih[q] : 0.f;
        asm volatile("" : "+v"(bias[r]), "+v"(wih[r]));
    }

    // own h state (4 rows); rows 30/31: acc==0 -> tanh_e2(0)=0 exactly.
    float h0 = 0.f, h1 = 0.f, h2 = 0.f, h3 = 0.f;

    const float* xp = x + (size_t)b * TT;
    const int NQ = TT / 4;
    float4 xq = *(const float4*)xp;
    float4 xn = *(const float4*)(xp + 4);

    for (int qq = 0; qq < NQ; ++qq) {
        const float4 xf = (qq + 2 < NQ) ? *(const float4*)(xp + (qq + 2) * 4)
                                        : make_float4(0.f, 0.f, 0.f, 0.f);
#pragma unroll
        for (int u = 0; u < 4; ++u) {
            const float xt = (u == 0) ? xq.x : (u == 1) ? xq.y
                           : (u == 2) ? xq.z : xq.w;
            const int p = u & 1;   // step parity (consecutive steps alternate)

            // 1. pack own h(t-1); ONE b128 publish
            unsigned hp0, hp1, lp0, lp1;
            BPAIR(h0, h1, hp0, lp0);
            BPAIR(h2, h3, hp1, lp1);
            E[p][wv][lane] = (uint4v){hp0, hp1, lp0, lp1};

            // 2. C-init (overlaps barrier wait)
            f32x4 acc = { fmaf(xt, wih[0], bias[0]), fmaf(xt, wih[1], bias[1]),
                          fmaf(xt, wih[2], bias[2]), fmaf(xt, wih[3], bias[3]) };

            // 3. exchange: ONE b128 read of partner's quad
            __syncthreads();
            const uint4v rv = E[p][wv ^ 1][lane];

            // 4. compose full B fragments (own words + partner words)
            uint4v bh, bl;
            if (wv == 0) { bh = (uint4v){hp0, hp1, rv[0], rv[1]};
                           bl = (uint4v){lp0, lp1, rv[2], rv[3]}; }
            else         { bh = (uint4v){rv[0], rv[1], hp0, hp1};
                           bl = (uint4v){rv[2], rv[3], lp0, lp1}; }
            const bf16x8 Bh = __builtin_bit_cast(bf16x8, bh);
            const bf16x8 Bl = __builtin_bit_cast(bf16x8, bl);

            // 5. MFMAs: 3 independent chains (R13 lesson), then 2 adds
            const f32x4 zed = {0.f, 0.f, 0.f, 0.f};
            acc = MFMA(Ah, Bh, acc);
            f32x4 q1 = MFMA(Ah, Bl, zed);
            f32x4 q2 = MFMA(Al, Bh, zed);
            const f32x4 s = (acc + q1) + q2;

            // 6. tanh (input pre-scaled by SCL)
            h0 = tanh_e2(s[0]); h1 = tanh_e2(s[1]);
            h2 = tanh_e2(s[2]); h3 = tanh_e2(s[3]);
        }
        xq = xn;
        xn = xf;
    }

    // ---- FC head: gather full h for the 8 real batches, wave 0 computes ----
    if (live) {
        hfc[n][8 * g + 4 * wv + 0] = h0;
        hfc[n][8 * g + 4 * wv + 1] = h1;
        hfc[n][8 * g + 4 * wv + 2] = h2;
        hfc[n][8 * g + 4 * wv + 3] = h3;
    }
    __syncthreads();
    if (wv == 0 && live) {
#pragma unroll
        for (int j = 0; j < 3; ++j) {
            const int c = g + 4 * j;          // covers c=0..9 exactly once
            if (c < CC) {
                float acc = b_fc[c];
#pragma unroll
                for (int k = 0; k < HH; ++k)
                    acc = fmaf(W_fc[c * HH + k], hfc[n][k], acc);
                out[(size_t)b * CC + c] = acc;
            }
        }
    }
}

extern "C" void kernel_launch(void* const* d_in, const int* in_sizes, int n_in,
                              void* d_out, int out_size, void* d_ws, size_t ws_size,
                              hipStream_t stream) {
    const float* x    = (const float*)d_in[0];
    const float* W_ih = (const float*)d_in[1];
    const float* W_hh = (const float*)d_in[2];
    const float* b_ih = (const float*)d_in[3];
    const float* b_hh = (const float*)d_in[4];
    const float* W_fc = (const float*)d_in[5];
    const float* b_fc = (const float*)d_in[6];

    hipLaunchKernelGGL(rnn_scan_kernel,
                       dim3(BB / 8), dim3(128), 0, stream,
                       x, W_ih, W_hh, b_ih, b_hh, W_fc, b_fc,
                       (float*)d_out);
}

// Round 14
// 312.819 us; speedup vs baseline: 1.1956x; 1.0273x over previous
//
#include <hip/hip_runtime.h>

// RNN: h_t = tanh(x_t * W_ih^T + b_ih + h_{t-1} W_hh^T + b_hh), out = h_T W_fc^T + b_fc
// B=8192, T=784, I=1, H=30 (pad 32), C=10. fp32.
//
// R16 = R12 geometry (16 batches/pair, 1024 waves, 1/SIMD -- the measured
// optimum of the decomposition lattice: R11 16b/wave-solo 713clk, R12
// 16b/pair 686clk, R15 8b/pair 857clk, 32b/wave ~960clk computed) +
// R15's proven exchange body:
//  * ONE b128 write + ONE b128 partner read per wave per step
//    (wave64 b128 DS ops phase 8 lanes across all 32 banks: R15 measured
//    0 bank conflicts vs R12's 6.4M from u64 stride-16B writes);
//  * B fragments composed from own REGISTERS + partner's quad
//    (halves read traffic vs R12's full-32B reads);
//  * 3 independent MFMA chains + 2 adds (R13 lesson).
// All other proven pieces unchanged: permuted-A zero-shuffle layout (R9),
// bf16 split-float with lo*lo dropped (R9), SCL=2*log2e folded into
// W/bias for exp2-direct tanh (R12), parity double-buffer with one
// barrier/step (R12), volatile pins (R6), x prefetch depth 2 (R11).
// Numerics identical to R12/R15: absmax must be exactly 0.001953125.

#define BB 8192
#define TT 784
#define HH 30
#define CC 10

typedef __attribute__((ext_vector_type(8))) short  bf16x8;
typedef __attribute__((ext_vector_type(4))) float  f32x4;
typedef __attribute__((ext_vector_type(4))) unsigned uint4v;

#if __has_builtin(__builtin_amdgcn_exp2f)
#define EXP2(v) __builtin_amdgcn_exp2f(v)
#else
#define EXP2(v) __expf((v) * 0.69314718055994531f)   // e^(x ln2) = 2^x
#endif

// pre-scale folded into W_hh/W_ih/bias: 2*log2(e)
#define SCL 2.8853900817779268f

__device__ __forceinline__ float tanh_e2(float s) {
    // s = 2*log2e*a ;  tanh(a) = 1 - 2/(2^s + 1)
    return 1.0f - 2.0f * __builtin_amdgcn_rcpf(EXP2(s) + 1.0f);
}

// (p0,p1) f32 -> packed bf16 pair hp (hi) + packed bf16 residual pair lp.
#define BPAIR(p0, p1, hp, lp) do {                                          \
    asm("v_cvt_pk_bf16_f32 %0, %1, %2" : "=v"(hp) : "v"(p0), "v"(p1));      \
    const float _h0 = __uint_as_float((hp) << 16);                          \
    const float _h1 = __uint_as_float((hp) & 0xffff0000u);                  \
    const float _l0 = (p0) - _h0;                                           \
    const float _l1 = (p1) - _h1;                                           \
    asm("v_cvt_pk_bf16_f32 %0, %1, %2" : "=v"(lp) : "v"(_l0), "v"(_l1));    \
} while (0)

#define MFMA(A, B, C) __builtin_amdgcn_mfma_f32_16x16x32_bf16((A), (B), (C), 0, 0, 0)

__global__ __launch_bounds__(128)
__attribute__((amdgpu_waves_per_eu(1, 1)))
void rnn_scan_kernel(const float* __restrict__ x,
                     const float* __restrict__ W_ih,
                     const float* __restrict__ W_hh,
                     const float* __restrict__ b_ih,
                     const float* __restrict__ b_hh,
                     const float* __restrict__ W_fc,
                     const float* __restrict__ b_fc,
                     float* __restrict__ out) {
    // E[parity][wv][lane] = writer wave's packed own-half {hp0,hp1,lp0,lp1}.
    // Single b128 write / single b128 read: 0 conflicts (R15 measured).
    __shared__ uint4v E[2][2][64];
    __shared__ float hfc[16][33];

    const int tid  = threadIdx.x;
    const int wv   = tid >> 6;        // 0: h rows j=0..3, 1: rows j=4..7
    const int lane = tid & 63;
    const int n    = lane & 15;       // A-tile row / B column
    const int g    = lane >> 4;       // k-group / D-row group
    const int b    = blockIdx.x * 16 + n;

    // ---- A fragment (R12-proven permutation) ----
    const int rr = 8 * (n >> 2) + (n & 3) + 4 * wv;   // 30,31 -> zero rows
    unsigned ah[4], al[4];
#pragma unroll
    for (int d = 0; d < 4; ++d) {
        const int k0 = 8 * g + 2 * d, k1 = k0 + 1;
        const float wa = (rr < HH && k0 < HH) ? SCL * W_hh[rr * HH + k0] : 0.f;
        const float wb = (rr < HH && k1 < HH) ? SCL * W_hh[rr * HH + k1] : 0.f;
        const unsigned ua = __float_as_uint(wa), ub = __float_as_uint(wb);
        ah[d] = (ub & 0xffff0000u) | (ua >> 16);
        const float la = wa - __uint_as_float(ua & 0xffff0000u);
        const float lb = wb - __uint_as_float(ub & 0xffff0000u);
        al[d] = (__float_as_uint(lb) & 0xffff0000u) | (__float_as_uint(la) >> 16);
    }
    bf16x8 Ah = __builtin_bit_cast(bf16x8, (uint4v){ah[0], ah[1], ah[2], ah[3]});
    bf16x8 Al = __builtin_bit_cast(bf16x8, (uint4v){al[0], al[1], al[2], al[3]});
    asm volatile("" : "+v"(Ah), "+v"(Al));

    // ---- C-init params: this lane+wave's D rows are h rows 8g+4wv+r ----
    float bias[4], wih[4];
#pragma unroll
    for (int r = 0; r < 4; ++r) {
        const int q = 8 * g + 4 * wv + r;             // 30,31 -> zero
        bias[r] = (q < HH) ? SCL * (b_ih[q] + b_hh[q]) : 0.f;
        wih[r]  = (q < HH) ? SCL * W_ih[q] : 0.f;
        asm volatile("" : "+v"(bias[r]), "+v"(wih[r]));
    }

    // own h state (4 rows); rows 30/31: acc==0 -> tanh_e2(0)=0 exactly.
    float h0 = 0.f, h1 = 0.f, h2 = 0.f, h3 = 0.f;

    const float* xp = x + (size_t)b * TT;
    const int NQ = TT / 4;
    float4 xq = *(const float4*)xp;
    float4 xn = *(const float4*)(xp + 4);

    for (int qq = 0; qq < NQ; ++qq) {
        const float4 xf = (qq + 2 < NQ) ? *(const float4*)(xp + (qq + 2) * 4)
                                        : make_float4(0.f, 0.f, 0.f, 0.f);
#pragma unroll
        for (int u = 0; u < 4; ++u) {
            const float xt = (u == 0) ? xq.x : (u == 1) ? xq.y
                           : (u == 2) ? xq.z : xq.w;
            const int p = u & 1;   // step parity (consecutive steps alternate)

            // 1. pack own h(t-1); ONE b128 publish
            unsigned hp0, hp1, lp0, lp1;
            BPAIR(h0, h1, hp0, lp0);
            BPAIR(h2, h3, hp1, lp1);
            E[p][wv][lane] = (uint4v){hp0, hp1, lp0, lp1};

            // 2. C-init (overlaps barrier wait)
            f32x4 acc = { fmaf(xt, wih[0], bias[0]), fmaf(xt, wih[1], bias[1]),
                          fmaf(xt, wih[2], bias[2]), fmaf(xt, wih[3], bias[3]) };

            // 3. exchange: ONE b128 read of partner's quad
            __syncthreads();
            const uint4v rv = E[p][wv ^ 1][lane];

            // 4. compose full B fragments (own regs + partner words)
            uint4v bh, bl;
            if (wv == 0) { bh = (uint4v){hp0, hp1, rv[0], rv[1]};
                           bl = (uint4v){lp0, lp1, rv[2], rv[3]}; }
            else         { bh = (uint4v){rv[0], rv[1], hp0, hp1};
                           bl = (uint4v){rv[2], rv[3], lp0, lp1}; }
            const bf16x8 Bh = __builtin_bit_cast(bf16x8, bh);
            const bf16x8 Bl = __builtin_bit_cast(bf16x8, bl);

            // 5. MFMAs: 3 independent chains (R13 lesson), then 2 adds
            const f32x4 zed = {0.f, 0.f, 0.f, 0.f};
            acc = MFMA(Ah, Bh, acc);
            f32x4 q1 = MFMA(Ah, Bl, zed);
            f32x4 q2 = MFMA(Al, Bh, zed);
            const f32x4 s = (acc + q1) + q2;

            // 6. tanh (input pre-scaled by SCL)
            h0 = tanh_e2(s[0]); h1 = tanh_e2(s[1]);
            h2 = tanh_e2(s[2]); h3 = tanh_e2(s[3]);
        }
        xq = xn;
        xn = xf;
    }

    // ---- FC head: gather full h per batch in LDS, wave 0 computes ----
    hfc[n][8 * g + 4 * wv + 0] = h0;
    hfc[n][8 * g + 4 * wv + 1] = h1;
    hfc[n][8 * g + 4 * wv + 2] = h2;
    hfc[n][8 * g + 4 * wv + 3] = h3;
    __syncthreads();
    if (wv == 0) {
#pragma unroll
        for (int j = 0; j < 3; ++j) {
            const int c = g + 4 * j;          // covers c=0..9 exactly once
            if (c < CC) {
                float acc = b_fc[c];
#pragma unroll
                for (int k = 0; k < HH; ++k)
                    acc = fmaf(W_fc[c * HH + k], hfc[n][k], acc);
                out[(size_t)b * CC + c] = acc;
            }
        }
    }
}

extern "C" void kernel_launch(void* const* d_in, const int* in_sizes, int n_in,
                              void* d_out, int out_size, void* d_ws, size_t ws_size,
                              hipStream_t stream) {
    const float* x    = (const float*)d_in[0];
    const float* W_ih = (const float*)d_in[1];
    const float* W_hh = (const float*)d_in[2];
    const float* b_ih = (const float*)d_in[3];
    const float* b_hh = (const float*)d_in[4];
    const float* W_fc = (const float*)d_in[5];
    const float* b_fc = (const float*)d_in[6];

    hipLaunchKernelGGL(rnn_scan_kernel,
                       dim3(BB / 16), dim3(128), 0, stream,
                       x, W_ih, W_hh, b_ih, b_hh, W_fc, b_fc,
                       (float*)d_out);
}